// Round 14
// baseline (575.697 us; speedup 1.0000x reference)
//
#include <hip/hip_runtime.h>
#include <hip/hip_bf16.h>
#include <math.h>

#define TT   2048
#define KK   48
#define KP   68             // epilogue staging pitch in ushorts

typedef __attribute__((ext_vector_type(8))) short bf16x8;
typedef __attribute__((ext_vector_type(4))) float f32x4;
typedef __attribute__((ext_vector_type(4))) unsigned int u32x4;
typedef unsigned short ushort_t;

union FragU { u32x4 u; bf16x8 h; };

__device__ __forceinline__ float rlf(float x, int l) {
    return __uint_as_float((unsigned)__builtin_amdgcn_readlane((int)__float_as_uint(x), l));
}
__device__ __forceinline__ unsigned pk2(float a, float b) {
    __hip_bfloat162 h = __float22bfloat162_rn(make_float2(a, b));
    return *(unsigned*)&h;
}
// HW pack: single v_cvt_pk_bf16_f32 (RNE; gfx950-verified R7)
__device__ __forceinline__ unsigned pk2a(float a, float b) {
    unsigned r;
    asm("v_cvt_pk_bf16_f32 %0, %1, %2" : "=v"(r) : "v"(a), "v"(b));
    return r;
}

// ---------------- Kernel 1 (R14): DUAL-chain segment products ----------------
// Two independent segment chains per wave (segs 2j, 2j+1), interleaved at
// column granularity so chain-A MFMA co-issues with chain-B VALU (R13 showed
// VALU 48% + MFMA 44% with poor overlap; ideal = max not sum). A-chain (even
// segs) is always full -> unguarded; B-chain carries the variable tail ->
// guarded every step. eL re-read per column from LDS to cut persistent regs.
template <int SEGT, int NSEGT>
__global__ __launch_bounds__(64, 4) void crf_seg2_kernel(
    const float* __restrict__ logits,   // [B, T, K]
    const float* __restrict__ trans,    // [K, K]
    const int*   __restrict__ lens,     // [B]
    ushort_t*    __restrict__ Qout,     // [B*NSEGT][48*48] bf16 row-major
    float*       __restrict__ sigout)   // [B*NSEGT]
{
    constexpr int NFULLT = NSEGT - 1;
    const int b    = blockIdx.x;
    const int segA = 2 * blockIdx.y;        // even: always full
    const int segB = segA + 1;              // odd: full except seg NFULLT
    const int jobA = b * NSEGT + segA;
    const int jobB = b * NSEGT + segB;
    const int lane = threadIdx.x;
    const int c = lane & 15, g = lane >> 4;

    const int t0A = SEGT * segA + 1;        // nstepsA == SEGT always
    int t0B, nstepsB;
    if (segB < NFULLT) { t0B = SEGT * segB + 1; nstepsB = SEGT; }
    else {
        int L  = lens[b];
        int nf = (L >= 2) ? (L - 1) / SEGT : 0;
        if (nf > NFULLT) nf = NFULLT;
        t0B = SEGT * nf + 1; nstepsB = L - t0B;   // may be <= 0 -> Q = I
    }

    __shared__ float    eLs[2][128];     // [par][0..63]=chain A, [64..127]=B
    __shared__ ushort_t Qst[KK * KP];    // epilogue staging (reused per chain)

    // Constant A fragments: A[mt][q], row r = 16mt + c,
    // k = 32q + 16*(e>>2) + 4g + (e&3); zero for k >= 48. (shared by chains)
    FragU A[3][2];
    #pragma unroll
    for (int mt = 0; mt < 3; ++mt) {
        const int r = 16 * mt + c;
        #pragma unroll
        for (int q = 0; q < 2; ++q) {
            #pragma unroll
            for (int ep = 0; ep < 4; ++ep) {
                float v0, v1;
                { int e = 2 * ep;     int kk = 32 * q + 16 * (e >> 2) + 4 * g + (e & 3);
                  v0 = (kk < KK) ? __expf(trans[kk * KK + r]) : 0.f; }
                { int e = 2 * ep + 1; int kk = 32 * q + 16 * (e >> 2) + 4 * g + (e & 3);
                  v1 = (kk < KK) ? __expf(trans[kk * KK + r]) : 0.f; }
                A[mt][q].u[ep] = pk2(v0, v1);
            }
        }
    }

    // Bf init = identity columns (both chains identical init).
    FragU BfA[3][2], BfB[3][2];
    #pragma unroll
    for (int nt = 0; nt < 3; ++nt) {
        const int n = 16 * nt + c;
        #pragma unroll
        for (int q = 0; q < 2; ++q) {
            #pragma unroll
            for (int ep = 0; ep < 4; ++ep) {
                int e0 = 2 * ep, e1 = 2 * ep + 1;
                int k0 = 32 * q + 16 * (e0 >> 2) + 4 * g + (e0 & 3);
                int k1 = 32 * q + 16 * (e1 >> 2) + 4 * g + (e1 & 3);
                unsigned lo = (k0 == n) ? 0x3F80u : 0u;
                unsigned hi = (k1 == n) ? 0x3F80u : 0u;
                BfA[nt][q].u[ep] = (hi << 16) | lo;
                BfB[nt][q].u[ep] = (hi << 16) | lo;
            }
        }
    }

    const float* lg_b = logits + (size_t)b * TT * KK;
    const int jj = (lane < KK) ? lane : 0;
    float sgA = 0.f, sgB = 0.f;

    f32x4 z4 = {0.f, 0.f, 0.f, 0.f};
    asm("" : "+v"(z4));

#define MFMA6(Y0_, Y1_, Y2_, BFA_, NT_)                                       \
    Y0_ = __builtin_amdgcn_mfma_f32_16x16x32_bf16(A[0][0].h, BFA_[NT_][0].h, z4, 0, 0, 0); \
    Y0_ = __builtin_amdgcn_mfma_f32_16x16x32_bf16(A[0][1].h, BFA_[NT_][1].h, Y0_, 0, 0, 0); \
    Y1_ = __builtin_amdgcn_mfma_f32_16x16x32_bf16(A[1][0].h, BFA_[NT_][0].h, z4, 0, 0, 0); \
    Y1_ = __builtin_amdgcn_mfma_f32_16x16x32_bf16(A[1][1].h, BFA_[NT_][1].h, Y1_, 0, 0, 0); \
    Y2_ = __builtin_amdgcn_mfma_f32_16x16x32_bf16(A[2][0].h, BFA_[NT_][0].h, z4, 0, 0, 0); \
    Y2_ = __builtin_amdgcn_mfma_f32_16x16x32_bf16(A[2][1].h, BFA_[NT_][1].h, Y2_, 0, 0, 0);

// Scale col NT_ by eL (per-column LDS reload; rr folded in on RN steps),
// cvt to bf16, store into BFA_[NT_]. GB_: guard with JK_ (B chain only).
#define SCL(Y0_, Y1_, Y2_, BFA_, NT_, EOFF_, RR_, RN_, GB_, JK_)              \
    {                                                                         \
        f32x4 e0 = *(const f32x4*)&eLs[par][(EOFF_) + 4 * g];                 \
        f32x4 e1 = *(const f32x4*)&eLs[par][(EOFF_) + 16 + 4 * g];            \
        f32x4 e2 = *(const f32x4*)&eLs[par][(EOFF_) + 32 + 4 * g];            \
        if (RN_) { e0 *= (RR_); e1 *= (RR_); e2 *= (RR_); }                   \
        f32x4 w0 = Y0_ * e0, w1 = Y1_ * e1, w2 = Y2_ * e2;                    \
        unsigned n0 = pk2a(w0[0], w0[1]);                                     \
        unsigned n1 = pk2a(w0[2], w0[3]);                                     \
        unsigned n2 = pk2a(w1[0], w1[1]);                                     \
        unsigned n3 = pk2a(w1[2], w1[3]);                                     \
        unsigned n4 = pk2a(w2[0], w2[1]);                                     \
        unsigned n5 = pk2a(w2[2], w2[3]);                                     \
        if (GB_) {                                                            \
            BFA_[NT_][0].u[0] = (JK_) ? BFA_[NT_][0].u[0] : n0;               \
            BFA_[NT_][0].u[1] = (JK_) ? BFA_[NT_][0].u[1] : n1;               \
            BFA_[NT_][0].u[2] = (JK_) ? BFA_[NT_][0].u[2] : n2;               \
            BFA_[NT_][0].u[3] = (JK_) ? BFA_[NT_][0].u[3] : n3;               \
            BFA_[NT_][1].u[0] = (JK_) ? BFA_[NT_][1].u[0] : n4;               \
            BFA_[NT_][1].u[1] = (JK_) ? BFA_[NT_][1].u[1] : n5;               \
        } else {                                                              \
            BFA_[NT_][0].u[0] = n0; BFA_[NT_][0].u[1] = n1;                   \
            BFA_[NT_][0].u[2] = n2; BFA_[NT_][0].u[3] = n3;                   \
            BFA_[NT_][1].u[0] = n4; BFA_[NT_][1].u[1] = n5;                   \
        }                                                                     \
    }

#define STEPP(u_, RN_)                                                        \
    {                                                                         \
        const int i = 8 * cs + (u_);                                          \
        float lgnA = pfA[((u_) + 1) & 3];                                     \
        int nrA = t0A + i + 5; if (nrA > TT - 1) nrA = TT - 1;                \
        pfA[((u_) + 1) & 3] = lg_b[nrA * KK + jj];                            \
        float lgnB = pfB[((u_) + 1) & 3];                                     \
        int nrB = t0B + i + 5; if (nrB > TT - 1) nrB = TT - 1;                \
        pfB[((u_) + 1) & 3] = lg_b[nrB * KK + jj];                            \
        if (lane < KK) {                                                      \
            eLs[par ^ 1][lane]      = __expf(lgnA);                           \
            eLs[par ^ 1][64 + lane] = __expf(lgnB);                           \
        }                                                                     \
        const bool jkB = (i >= nstepsB);                                      \
        f32x4 yA0, yA1, yA2, yB0, yB1, yB2;                                   \
        float rrA = 1.f, rrB = 1.f;                                           \
        MFMA6(yA0, yA1, yA2, BfA, 0)                                          \
        MFMA6(yB0, yB1, yB2, BfB, 0)                                          \
        if (RN_) {                                                            \
            float rA_ = rlf(yA0[0], 0);                                       \
            rrA = __builtin_amdgcn_rcpf(rA_);                                 \
            sgA += __logf(rA_);                                               \
            float rB_ = rlf(yB0[0], 0);                                       \
            rrB = __builtin_amdgcn_rcpf(rB_);                                 \
            sgB += jkB ? 0.f : __logf(rB_);                                   \
        }                                                                     \
        SCL(yA0, yA1, yA2, BfA, 0, 0,  rrA, RN_, false, false)                \
        SCL(yB0, yB1, yB2, BfB, 0, 64, rrB, RN_, true,  jkB)                  \
        MFMA6(yA0, yA1, yA2, BfA, 1)                                          \
        MFMA6(yB0, yB1, yB2, BfB, 1)                                          \
        SCL(yA0, yA1, yA2, BfA, 1, 0,  rrA, RN_, false, false)                \
        SCL(yB0, yB1, yB2, BfB, 1, 64, rrB, RN_, true,  jkB)                  \
        MFMA6(yA0, yA1, yA2, BfA, 2)                                          \
        MFMA6(yB0, yB1, yB2, BfB, 2)                                          \
        SCL(yA0, yA1, yA2, BfA, 2, 0,  rrA, RN_, false, false)                \
        SCL(yB0, yB1, yB2, BfB, 2, 64, rrB, RN_, true,  jkB)                  \
        par ^= 1;                                                             \
    }

    int par = 0;
    {
        // Prologue: eL for step 0 of both chains; 4-deep prefetch rings.
        if (lane < KK) {
            eLs[0][lane]      = __expf(lg_b[t0A * KK + jj]);
            int r0B = t0B; if (r0B > TT - 1) r0B = TT - 1;
            eLs[0][64 + lane] = __expf(lg_b[r0B * KK + jj]);
        }
        float pfA[4], pfB[4];
        #pragma unroll
        for (int j = 1; j < 4; ++j) {
            int rjA = t0A + j; if (rjA > TT - 1) rjA = TT - 1;
            pfA[j] = lg_b[rjA * KK + jj];
            int rjB = t0B + j; if (rjB > TT - 1) rjB = TT - 1;
            pfB[j] = lg_b[rjB * KK + jj];
        }
        { int r4A = t0A + 4; if (r4A > TT - 1) r4A = TT - 1; pfA[0] = lg_b[r4A * KK + jj]; }
        { int r4B = t0B + 4; if (r4B > TT - 1) r4B = TT - 1; pfB[0] = lg_b[r4B * KK + jj]; }

        constexpr int NCH = SEGT / 8;
        #pragma unroll 1
        for (int cs = 0; cs < NCH; ++cs) {
            STEPP(0, false) STEPP(1, false) STEPP(2, false) STEPP(3, true)
            STEPP(4, false) STEPP(5, false) STEPP(6, false) STEPP(7, true)
        }
    }
#undef STEPP
#undef SCL
#undef MFMA6

    // ---- epilogue: stage + store each chain's Q (bf16) ----
#define EPI(BFA_, JOB_, SG_)                                                  \
    {                                                                         \
        __syncthreads();                                                      \
        _Pragma("unroll")                                                     \
        for (int nt = 0; nt < 3; ++nt) {                                      \
            ushort_t* basep = &Qst[(16 * nt + c) * KP];                       \
            *(unsigned*)&basep[4 * g]          = BFA_[nt][0].u[0];            \
            *(unsigned*)&basep[4 * g + 2]      = BFA_[nt][0].u[1];            \
            *(unsigned*)&basep[16 + 4 * g]     = BFA_[nt][0].u[2];            \
            *(unsigned*)&basep[16 + 4 * g + 2] = BFA_[nt][0].u[3];            \
            *(unsigned*)&basep[32 + 4 * g]     = BFA_[nt][1].u[0];            \
            *(unsigned*)&basep[32 + 4 * g + 2] = BFA_[nt][1].u[1];            \
        }                                                                     \
        __syncthreads();                                                      \
        if (lane < KK) {                                                      \
            const int m = lane;                                               \
            unsigned w[24];                                                   \
            _Pragma("unroll")                                                 \
            for (int np = 0; np < 24; ++np) {                                 \
                unsigned lo = Qst[(2 * np)     * KP + m];                     \
                unsigned hi = Qst[(2 * np + 1) * KP + m];                     \
                w[np] = (hi << 16) | lo;                                      \
            }                                                                 \
            ushort_t* dst = Qout + (size_t)(JOB_) * (KK * KK) + m * KK;       \
            _Pragma("unroll")                                                 \
            for (int i4 = 0; i4 < 6; ++i4) {                                  \
                uint4 o; o.x = w[4*i4]; o.y = w[4*i4+1];                      \
                o.z = w[4*i4+2]; o.w = w[4*i4+3];                             \
                *(uint4*)&dst[8 * i4] = o;                                    \
            }                                                                 \
        }                                                                     \
        if (lane == 0) sigout[JOB_] = SG_;                                    \
    }
    EPI(BfA, jobA, sgA)
    EPI(BfB, jobB, sgB)
#undef EPI
}

// ---------------- Kernel 2: per-batch combine + scores (proven R5-R13) ----
template <int SEGT, int NSEGT>
__global__ __launch_bounds__(64) void crf_comb_kernel(
    const float* __restrict__ logits, const float* __restrict__ trans,
    const int* __restrict__ targets, const int* __restrict__ lens,
    const ushort_t* __restrict__ Qall, const float* __restrict__ sig,
    float* __restrict__ out)
{
    constexpr int NFULLT = NSEGT - 1;
    const int b = blockIdx.x, lane = threadIdx.x;
    const int jj = (lane < KK) ? lane : 0;
    const int L = lens[b];

    __shared__ float s_trans[KK * KK];
    for (int k = lane; k < KK * KK; k += 64) s_trans[k] = trans[k];
    __syncthreads();

    const float* lg_b = logits  + (size_t)b * TT * KK;
    const int*   tg_b = targets + (size_t)b * TT;

    float ub = 0.f;
    #pragma unroll 4
    for (int t = lane; t < TT; t += 64) {
        if (t < L) {
            int tg = tg_b[t];
            ub += lg_b[t * KK + tg];
            if (t >= 1) { int tp = tg_b[t - 1]; ub += s_trans[tp * KK + tg]; }
        }
    }
    #pragma unroll
    for (int d = 32; d >= 1; d >>= 1) ub += __shfl_xor(ub, d, 64);

    float log_norm = 0.f;
    if (L > 0) {
        float a0 = lg_b[jj];
        float M  = rlf(a0, 0);
        float s  = (lane < KK) ? __expf(a0 - M) : 0.f;
        int nf = (L >= 2) ? (L - 1) / SEGT : 0;
        if (nf > NFULLT) nf = NFULLT;

        for (int ci = 0; ci <= nf; ++ci) {           // full segments, then tail
            const int job = b * NSEGT + ((ci < nf) ? ci : NFULLT);
            const ushort_t* Qr = Qall + (size_t)job * (KK * KK) + jj * KK;
            unsigned rw[24];
            #pragma unroll
            for (int i4 = 0; i4 < 6; ++i4) {
                uint4 v = *(const uint4*)&Qr[8 * i4];
                rw[4*i4] = v.x; rw[4*i4+1] = v.y; rw[4*i4+2] = v.z; rw[4*i4+3] = v.w;
            }
            float acc = 0.f;
            #pragma unroll
            for (int ip = 0; ip < 24; ++ip) {
                unsigned u = rw[ip];
                float q0 = __uint_as_float(u << 16);
                float q1 = __uint_as_float(u & 0xFFFF0000u);
                acc = fmaf(rlf(s, 2 * ip),     q0, acc);
                acc = fmaf(rlf(s, 2 * ip + 1), q1, acc);
            }
            float r  = rlf(acc, 0);
            float rr = __builtin_amdgcn_rcpf(r);
            s = (lane < KK) ? acc * rr : 0.f;
            M += __logf(r) + sig[job];
        }

        float ssum = (lane < KK) ? s : 0.f;
        #pragma unroll
        for (int d = 32; d >= 1; d >>= 1) ssum += __shfl_xor(ssum, d, 64);
        log_norm = M + __logf(ssum);
    }

    if (lane == 0) out[b] = (L <= 0) ? 0.f : (ub - log_norm);
}

// ---------------- Round-3 fallback (ws too small) ----------------
__global__ __launch_bounds__(64) void crf_fwd_fallback(
    const float* __restrict__ logits, const float* __restrict__ trans,
    const int* __restrict__ targets, const int* __restrict__ lens,
    float* __restrict__ out)
{
    const int b = blockIdx.x, lane = threadIdx.x;
    const int jj = (lane < KK) ? lane : 0;
    const int L = lens[b];
    __shared__ float s_trans[KK * KK];
    for (int k = lane; k < KK * KK; k += 64) s_trans[k] = trans[k];
    float et[KK];
    #pragma unroll
    for (int i = 0; i < KK; ++i) et[i] = __expf(trans[i * KK + jj]);
    __syncthreads();
    const float* lg_b = logits + (size_t)b * TT * KK;
    const int* tg_b = targets + (size_t)b * TT;
    float ub = 0.f;
    for (int t = lane; t < TT; t += 64) {
        if (t < L) {
            int tg = tg_b[t];
            ub += lg_b[t * KK + tg];
            if (t >= 1) { int tp = tg_b[t - 1]; ub += s_trans[tp * KK + tg]; }
        }
    }
    #pragma unroll
    for (int d = 32; d >= 1; d >>= 1) ub += __shfl_xor(ub, d, 64);
    float a0 = lg_b[jj];
    float M = rlf(a0, 0);
    float s = (lane < KK) ? __expf(a0 - M) : 0.f;
    float sC = s, MC = M;
    const int Lm1 = L - 1;
    float pf[8];
    #pragma unroll
    for (int u = 0; u < 8; ++u) pf[u] = lg_b[(1 + u) * KK + jj];
    #pragma unroll 1
    for (int cc = 0; cc < 256; ++cc) {
        #pragma unroll
        for (int u = 0; u < 8; ++u) {
            const int t = 1 + cc * 8 + u;
            float lg = pf[u];
            int nrow = t + 8; if (nrow > TT - 1) nrow = TT - 1;
            pf[u] = lg_b[nrow * KK + jj];
            float eL = __expf(lg);
            float ac0 = 0.f, ac1 = 0.f, ac2 = 0.f, ac3 = 0.f;
            #pragma unroll
            for (int i = 0; i < KK; i += 4) {
                float s0 = rlf(s, i), s1 = rlf(s, i+1), s2 = rlf(s, i+2), s3 = rlf(s, i+3);
                ac0 = fmaf(s0, et[i], ac0);   ac1 = fmaf(s1, et[i+1], ac1);
                ac2 = fmaf(s2, et[i+2], ac2); ac3 = fmaf(s3, et[i+3], ac3);
            }
            float e = ((ac0 + ac1) + (ac2 + ac3)) * eL;
            bool cap = (t == Lm1);
            sC = cap ? e : sC;  MC = cap ? M : MC;
            float r = rlf(e, 0);
            s = e * __builtin_amdgcn_rcpf(r);
            M += __logf(r);
        }
    }
    float ssum = (lane < KK) ? sC : 0.f;
    #pragma unroll
    for (int d = 32; d >= 1; d >>= 1) ssum += __shfl_xor(ssum, d, 64);
    float log_norm = MC + __logf(ssum);
    if (lane == 0) out[b] = (L <= 0) ? 0.f : (ub - log_norm);
}

extern "C" void kernel_launch(void* const* d_in, const int* in_sizes, int n_in,
                              void* d_out, int out_size, void* d_ws, size_t ws_size,
                              hipStream_t stream) {
    const float* logits  = (const float*)d_in[0];
    const float* trans   = (const float*)d_in[1];
    const int*   targets = (const int*)  d_in[2];
    const int*   lens    = (const int*)  d_in[3];
    float*       out     = (float*)d_out;
    const int B = in_sizes[3];

    const size_t q64 = (size_t)B * 32 * KK * KK * sizeof(ushort_t);
    const size_t n64 = q64 + (size_t)B * 32 * sizeof(float);

    if (ws_size >= n64) {
        ushort_t* Qout = (ushort_t*)d_ws;
        float*    sig  = (float*)((char*)d_ws + q64);
        crf_seg2_kernel<64, 32><<<dim3(B, 16), 64, 0, stream>>>(logits, trans, lens, Qout, sig);
        crf_comb_kernel<64, 32><<<B, 64, 0, stream>>>(logits, trans, targets, lens, Qout, sig, out);
    } else {
        crf_fwd_fallback<<<B, 64, 0, stream>>>(logits, trans, targets, lens, out);
    }
}

// Round 15
// 169.467 us; speedup vs baseline: 3.3971x; 3.3971x over previous
//
#include <hip/hip_runtime.h>
#include <hip/hip_bf16.h>
#include <math.h>

#define TT   2048
#define KK   48
#define KP   68             // epilogue staging pitch in ushorts

typedef __attribute__((ext_vector_type(8))) short bf16x8;
typedef __attribute__((ext_vector_type(4))) float f32x4;
typedef __attribute__((ext_vector_type(4))) unsigned int u32x4;
typedef unsigned short ushort_t;

union FragU { u32x4 u; bf16x8 h; };

__device__ __forceinline__ float rlf(float x, int l) {
    return __uint_as_float((unsigned)__builtin_amdgcn_readlane((int)__float_as_uint(x), l));
}
__device__ __forceinline__ unsigned pk2(float a, float b) {
    __hip_bfloat162 h = __float22bfloat162_rn(make_float2(a, b));
    return *(unsigned*)&h;
}
// HW pack: single v_cvt_pk_bf16_f32 (RNE; gfx950-verified R7: -45us)
__device__ __forceinline__ unsigned pk2a(float a, float b) {
    unsigned r;
    asm("v_cvt_pk_bf16_f32 %0, %1, %2" : "=v"(r) : "v"(a), "v"(b));
    return r;
}

// ---------------- Kernel 1: segment matrix products (R13 + setprio) ----------
// R15 = R13 (best known: 149us seg) + s_setprio(1) around each step's MFMA
// cluster. R13 PMC: MFMA 44% + VALU 48%, 3 waves/SIMD, no barriers ->
// phase-locked convoys (all waves burst MFMA together, then VALU together).
// setprio de-phases: the attn regime where m191 measured +4-7%.
// R14's dual-chain is dead: 2x chain state spilled to scratch (WRITE 987MB).
template <int SEGT, int NSEGT>
__global__ __launch_bounds__(64, 4) void crf_seg_kernel(
    const float* __restrict__ logits,   // [B, T, K]
    const float* __restrict__ trans,    // [K, K]
    const int*   __restrict__ lens,     // [B]
    ushort_t*    __restrict__ Qout,     // [B*NSEGT][48*48] bf16 row-major
    float*       __restrict__ sigout)   // [B*NSEGT]
{
    constexpr int NFULLT = NSEGT - 1;
    const int b    = blockIdx.x;
    const int seg  = blockIdx.y;        // 0..NSEGT-1
    const int job  = b * NSEGT + seg;
    const int lane = threadIdx.x;
    const int c = lane & 15, g = lane >> 4;

    int t0, t1;
    if (seg < NFULLT) { t0 = SEGT * seg + 1; t1 = SEGT * seg + SEGT; }
    else {
        int L  = lens[b];
        int nf = (L >= 2) ? (L - 1) / SEGT : 0;
        if (nf > NFULLT) nf = NFULLT;
        t0 = SEGT * nf + 1; t1 = L - 1;   // may be empty (t1 < t0) -> Q = I
    }

    __shared__ float    eLs[2][64];
    __shared__ ushort_t Qst[KK * KP];    // epilogue staging only

    // Constant A fragments: A[mt][q], row r = 16mt + c, k per bijection
    // k = 32q + 16*(e>>2) + 4g + (e&3); zero for k >= 48.
    FragU A[3][2];
    #pragma unroll
    for (int mt = 0; mt < 3; ++mt) {
        const int r = 16 * mt + c;
        #pragma unroll
        for (int q = 0; q < 2; ++q) {
            #pragma unroll
            for (int ep = 0; ep < 4; ++ep) {
                float v0, v1;
                { int e = 2 * ep;     int kk = 32 * q + 16 * (e >> 2) + 4 * g + (e & 3);
                  v0 = (kk < KK) ? __expf(trans[kk * KK + r]) : 0.f; }
                { int e = 2 * ep + 1; int kk = 32 * q + 16 * (e >> 2) + 4 * g + (e & 3);
                  v1 = (kk < KK) ? __expf(trans[kk * KK + r]) : 0.f; }
                A[mt][q].u[ep] = pk2(v0, v1);
            }
        }
    }

    // Bf init = identity columns: elem (q,e) of tile nt = I[k][16nt+c].
    FragU Bf[3][2];
    #pragma unroll
    for (int nt = 0; nt < 3; ++nt) {
        const int n = 16 * nt + c;
        #pragma unroll
        for (int q = 0; q < 2; ++q) {
            #pragma unroll
            for (int ep = 0; ep < 4; ++ep) {
                int e0 = 2 * ep, e1 = 2 * ep + 1;
                int k0 = 32 * q + 16 * (e0 >> 2) + 4 * g + (e0 & 3);
                int k1 = 32 * q + 16 * (e1 >> 2) + 4 * g + (e1 & 3);
                unsigned lo = (k0 == n) ? 0x3F80u : 0u;
                unsigned hi = (k1 == n) ? 0x3F80u : 0u;
                Bf[nt][q].u[ep] = (hi << 16) | lo;
            }
        }
    }

    const float* lg_b = logits + (size_t)b * TT * KK;
    const int jj = (lane < KK) ? lane : 0;
    float sg = 0.f;
    const int nsteps = t1 - t0 + 1;

    f32x4 z4 = {0.f, 0.f, 0.f, 0.f};
    asm("" : "+v"(z4));

// Scale col nt_'s y0..y2 by es, cvt to bf16, store into Bf[nt_] (guarded).
#define SCALE_STORE(nt_)                                                      \
    {                                                                         \
        f32x4 w0 = y0 * es0, w1 = y1 * es1, w2 = y2 * es2;                    \
        unsigned n0 = pk2a(w0[0], w0[1]);                                     \
        unsigned n1 = pk2a(w0[2], w0[3]);                                     \
        unsigned n2 = pk2a(w1[0], w1[1]);                                     \
        unsigned n3 = pk2a(w1[2], w1[3]);                                     \
        unsigned n4 = pk2a(w2[0], w2[1]);                                     \
        unsigned n5 = pk2a(w2[2], w2[3]);                                     \
        if (G_) {                                                             \
            Bf[nt_][0].u[0] = jk ? Bf[nt_][0].u[0] : n0;                      \
            Bf[nt_][0].u[1] = jk ? Bf[nt_][0].u[1] : n1;                      \
            Bf[nt_][0].u[2] = jk ? Bf[nt_][0].u[2] : n2;                      \
            Bf[nt_][0].u[3] = jk ? Bf[nt_][0].u[3] : n3;                      \
            Bf[nt_][1].u[0] = jk ? Bf[nt_][1].u[0] : n4;                      \
            Bf[nt_][1].u[1] = jk ? Bf[nt_][1].u[1] : n5;                      \
        } else {                                                              \
            Bf[nt_][0].u[0] = n0; Bf[nt_][0].u[1] = n1;                       \
            Bf[nt_][0].u[2] = n2; Bf[nt_][0].u[3] = n3;                       \
            Bf[nt_][1].u[0] = n4; Bf[nt_][1].u[1] = n5;                       \
        }                                                                     \
    }

#define COL_MFMA(nt_)                                                         \
        __builtin_amdgcn_s_setprio(1);                                        \
        y0 = __builtin_amdgcn_mfma_f32_16x16x32_bf16(A[0][0].h, Bf[nt_][0].h, z4, 0, 0, 0); \
        y0 = __builtin_amdgcn_mfma_f32_16x16x32_bf16(A[0][1].h, Bf[nt_][1].h, y0, 0, 0, 0); \
        y1 = __builtin_amdgcn_mfma_f32_16x16x32_bf16(A[1][0].h, Bf[nt_][0].h, z4, 0, 0, 0); \
        y1 = __builtin_amdgcn_mfma_f32_16x16x32_bf16(A[1][1].h, Bf[nt_][1].h, y1, 0, 0, 0); \
        y2 = __builtin_amdgcn_mfma_f32_16x16x32_bf16(A[2][0].h, Bf[nt_][0].h, z4, 0, 0, 0); \
        y2 = __builtin_amdgcn_mfma_f32_16x16x32_bf16(A[2][1].h, Bf[nt_][1].h, y2, 0, 0, 0); \
        __builtin_amdgcn_s_setprio(0);

// RN_: renormalize this step (every 4th: u_ = 3, 7).
#define STEP(u_, GG_, RN_)                                                    \
    {                                                                         \
        constexpr bool G_ = (GG_);                                            \
        const int i = 8 * cs + (u_);                                          \
        f32x4 eL0 = *(const f32x4*)&eLs[par][4 * g];                          \
        f32x4 eL1 = *(const f32x4*)&eLs[par][16 + 4 * g];                     \
        f32x4 eL2 = *(const f32x4*)&eLs[par][32 + 4 * g];                     \
        float lgn = pf[((u_) + 1) & 7];                                       \
        int nr = t0 + i + 9; if (nr > TT - 1) nr = TT - 1;                    \
        pf[((u_) + 1) & 7] = lg_b[nr * KK + jj];                              \
        if (lane < KK) eLs[par ^ 1][lane] = __expf(lgn);                      \
        const bool jk = G_ ? (i >= nsteps) : false;                           \
        f32x4 y0, y1, y2;                                                     \
        COL_MFMA(0)                                                           \
        f32x4 es0, es1, es2;                                                  \
        if (RN_) {                                                            \
            float r = __uint_as_float((unsigned)                              \
                __builtin_amdgcn_readfirstlane((int)__float_as_uint(y0[0]))); \
            float rr = __builtin_amdgcn_rcpf(r);                              \
            sg += jk ? 0.f : __logf(r);                                       \
            es0 = eL0 * rr; es1 = eL1 * rr; es2 = eL2 * rr;                   \
        } else {                                                              \
            es0 = eL0; es1 = eL1; es2 = eL2;                                  \
        }                                                                     \
        SCALE_STORE(0)                                                        \
        COL_MFMA(1)                                                           \
        SCALE_STORE(1)                                                        \
        COL_MFMA(2)                                                           \
        SCALE_STORE(2)                                                        \
        par ^= 1;                                                             \
    }

    int par = 0;
    if (nsteps > 0) {
        if (lane < KK) eLs[0][lane] = __expf(lg_b[t0 * KK + jj]);
        float pf[8];
        #pragma unroll
        for (int j = 1; j < 8; ++j) {
            int rj = t0 + j; if (rj > TT - 1) rj = TT - 1;
            pf[j] = lg_b[rj * KK + jj];
        }
        { int rj = t0 + 8; if (rj > TT - 1) rj = TT - 1; pf[0] = lg_b[rj * KK + jj]; }

        const int nchunks = (nsteps + 7) / 8;
        #pragma unroll 1
        for (int cs = 0; cs < nchunks - 1; ++cs) {
            STEP(0, false, false) STEP(1, false, false)
            STEP(2, false, false) STEP(3, false, true)
            STEP(4, false, false) STEP(5, false, false)
            STEP(6, false, false) STEP(7, false, true)
        }
        {   // last chunk: junk-guarded (freezes Bf/sg for i >= nsteps)
            const int cs = nchunks - 1;
            STEP(0, true, false) STEP(1, true, false)
            STEP(2, true, false) STEP(3, true, true)
            STEP(4, true, false) STEP(5, true, false)
            STEP(6, true, false) STEP(7, true, true)
        }
    }
#undef STEP
#undef COL_MFMA
#undef SCALE_STORE

    // ---- epilogue: stage Bf (= final Q, bf16, maybe unnormalized) to LDS ----
    #pragma unroll
    for (int nt = 0; nt < 3; ++nt) {
        ushort_t* basep = &Qst[(16 * nt + c) * KP];
        *(unsigned*)&basep[4 * g]          = Bf[nt][0].u[0];
        *(unsigned*)&basep[4 * g + 2]      = Bf[nt][0].u[1];
        *(unsigned*)&basep[16 + 4 * g]     = Bf[nt][0].u[2];
        *(unsigned*)&basep[16 + 4 * g + 2] = Bf[nt][0].u[3];
        *(unsigned*)&basep[32 + 4 * g]     = Bf[nt][1].u[0];
        *(unsigned*)&basep[32 + 4 * g + 2] = Bf[nt][1].u[1];
    }
    __syncthreads();

    if (lane < KK) {
        const int m = lane;
        unsigned w[24];
        #pragma unroll
        for (int np = 0; np < 24; ++np) {
            unsigned lo = Qst[(2 * np)     * KP + m];
            unsigned hi = Qst[(2 * np + 1) * KP + m];
            w[np] = (hi << 16) | lo;
        }
        ushort_t* dst = Qout + (size_t)job * (KK * KK) + m * KK;
        #pragma unroll
        for (int i4 = 0; i4 < 6; ++i4) {
            uint4 o; o.x = w[4*i4]; o.y = w[4*i4+1]; o.z = w[4*i4+2]; o.w = w[4*i4+3];
            *(uint4*)&dst[8 * i4] = o;
        }
    }
    if (lane == 0) sigout[job] = sg;
}

// ---------------- Kernel 2: per-batch combine + scores (proven R5-R13) ----
template <int SEGT, int NSEGT>
__global__ __launch_bounds__(64) void crf_comb_kernel(
    const float* __restrict__ logits, const float* __restrict__ trans,
    const int* __restrict__ targets, const int* __restrict__ lens,
    const ushort_t* __restrict__ Qall, const float* __restrict__ sig,
    float* __restrict__ out)
{
    constexpr int NFULLT = NSEGT - 1;
    const int b = blockIdx.x, lane = threadIdx.x;
    const int jj = (lane < KK) ? lane : 0;
    const int L = lens[b];

    __shared__ float s_trans[KK * KK];
    for (int k = lane; k < KK * KK; k += 64) s_trans[k] = trans[k];
    __syncthreads();

    const float* lg_b = logits  + (size_t)b * TT * KK;
    const int*   tg_b = targets + (size_t)b * TT;

    float ub = 0.f;
    #pragma unroll 4
    for (int t = lane; t < TT; t += 64) {
        if (t < L) {
            int tg = tg_b[t];
            ub += lg_b[t * KK + tg];
            if (t >= 1) { int tp = tg_b[t - 1]; ub += s_trans[tp * KK + tg]; }
        }
    }
    #pragma unroll
    for (int d = 32; d >= 1; d >>= 1) ub += __shfl_xor(ub, d, 64);

    float log_norm = 0.f;
    if (L > 0) {
        float a0 = lg_b[jj];
        float M  = rlf(a0, 0);
        float s  = (lane < KK) ? __expf(a0 - M) : 0.f;
        int nf = (L >= 2) ? (L - 1) / SEGT : 0;
        if (nf > NFULLT) nf = NFULLT;

        for (int ci = 0; ci <= nf; ++ci) {           // full segments, then tail
            const int job = b * NSEGT + ((ci < nf) ? ci : NFULLT);
            const ushort_t* Qr = Qall + (size_t)job * (KK * KK) + jj * KK;
            unsigned rw[24];
            #pragma unroll
            for (int i4 = 0; i4 < 6; ++i4) {
                uint4 v = *(const uint4*)&Qr[8 * i4];
                rw[4*i4] = v.x; rw[4*i4+1] = v.y; rw[4*i4+2] = v.z; rw[4*i4+3] = v.w;
            }
            float acc = 0.f;
            #pragma unroll
            for (int ip = 0; ip < 24; ++ip) {
                unsigned u = rw[ip];
                float q0 = __uint_as_float(u << 16);
                float q1 = __uint_as_float(u & 0xFFFF0000u);
                acc = fmaf(rlf(s, 2 * ip),     q0, acc);
                acc = fmaf(rlf(s, 2 * ip + 1), q1, acc);
            }
            float r  = rlf(acc, 0);
            float rr = __builtin_amdgcn_rcpf(r);
            s = (lane < KK) ? acc * rr : 0.f;
            M += __logf(r) + sig[job];
        }

        float ssum = (lane < KK) ? s : 0.f;
        #pragma unroll
        for (int d = 32; d >= 1; d >>= 1) ssum += __shfl_xor(ssum, d, 64);
        log_norm = M + __logf(ssum);
    }

    if (lane == 0) out[b] = (L <= 0) ? 0.f : (ub - log_norm);
}

// ---------------- Round-3 fallback (ws too small) ----------------
__global__ __launch_bounds__(64) void crf_fwd_fallback(
    const float* __restrict__ logits, const float* __restrict__ trans,
    const int* __restrict__ targets, const int* __restrict__ lens,
    float* __restrict__ out)
{
    const int b = blockIdx.x, lane = threadIdx.x;
    const int jj = (lane < KK) ? lane : 0;
    const int L = lens[b];
    __shared__ float s_trans[KK * KK];
    for (int k = lane; k < KK * KK; k += 64) s_trans[k] = trans[k];
    float et[KK];
    #pragma unroll
    for (int i = 0; i < KK; ++i) et[i] = __expf(trans[i * KK + jj]);
    __syncthreads();
    const float* lg_b = logits + (size_t)b * TT * KK;
    const int* tg_b = targets + (size_t)b * TT;
    float ub = 0.f;
    for (int t = lane; t < TT; t += 64) {
        if (t < L) {
            int tg = tg_b[t];
            ub += lg_b[t * KK + tg];
            if (t >= 1) { int tp = tg_b[t - 1]; ub += s_trans[tp * KK + tg]; }
        }
    }
    #pragma unroll
    for (int d = 32; d >= 1; d >>= 1) ub += __shfl_xor(ub, d, 64);
    float a0 = lg_b[jj];
    float M = rlf(a0, 0);
    float s = (lane < KK) ? __expf(a0 - M) : 0.f;
    float sC = s, MC = M;
    const int Lm1 = L - 1;
    float pf[8];
    #pragma unroll
    for (int u = 0; u < 8; ++u) pf[u] = lg_b[(1 + u) * KK + jj];
    #pragma unroll 1
    for (int cc = 0; cc < 256; ++cc) {
        #pragma unroll
        for (int u = 0; u < 8; ++u) {
            const int t = 1 + cc * 8 + u;
            float lg = pf[u];
            int nrow = t + 8; if (nrow > TT - 1) nrow = TT - 1;
            pf[u] = lg_b[nrow * KK + jj];
            float eL = __expf(lg);
            float ac0 = 0.f, ac1 = 0.f, ac2 = 0.f, ac3 = 0.f;
            #pragma unroll
            for (int i = 0; i < KK; i += 4) {
                float s0 = rlf(s, i), s1 = rlf(s, i+1), s2 = rlf(s, i+2), s3 = rlf(s, i+3);
                ac0 = fmaf(s0, et[i], ac0);   ac1 = fmaf(s1, et[i+1], ac1);
                ac2 = fmaf(s2, et[i+2], ac2); ac3 = fmaf(s3, et[i+3], ac3);
            }
            float e = ((ac0 + ac1) + (ac2 + ac3)) * eL;
            bool cap = (t == Lm1);
            sC = cap ? e : sC;  MC = cap ? M : MC;
            float r = rlf(e, 0);
            s = e * __builtin_amdgcn_rcpf(r);
            M += __logf(r);
        }
    }
    float ssum = (lane < KK) ? sC : 0.f;
    #pragma unroll
    for (int d = 32; d >= 1; d >>= 1) ssum += __shfl_xor(ssum, d, 64);
    float log_norm = MC + __logf(ssum);
    if (lane == 0) out[b] = (L <= 0) ? 0.f : (ub - log_norm);
}

extern "C" void kernel_launch(void* const* d_in, const int* in_sizes, int n_in,
                              void* d_out, int out_size, void* d_ws, size_t ws_size,
                              hipStream_t stream) {
    const float* logits  = (const float*)d_in[0];
    const float* trans   = (const float*)d_in[1];
    const int*   targets = (const int*)  d_in[2];
    const int*   lens    = (const int*)  d_in[3];
    float*       out     = (float*)d_out;
    const int B = in_sizes[3];

    const size_t q64  = (size_t)B * 32 * KK * KK * sizeof(ushort_t);
    const size_t n64  = q64 + (size_t)B * 32 * sizeof(float);
    const size_t q128 = (size_t)B * 16 * KK * KK * sizeof(ushort_t);
    const size_t n128 = q128 + (size_t)B * 16 * sizeof(float);

    if (ws_size >= n64) {
        ushort_t* Qout = (ushort_t*)d_ws;
        float*    sig  = (float*)((char*)d_ws + q64);
        crf_seg_kernel<64, 32><<<dim3(B, 32), 64, 0, stream>>>(logits, trans, lens, Qout, sig);
        crf_comb_kernel<64, 32><<<B, 64, 0, stream>>>(logits, trans, targets, lens, Qout, sig, out);
    } else if (ws_size >= n128) {
        ushort_t* Qout = (ushort_t*)d_ws;
        float*    sig  = (float*)((char*)d_ws + q128);
        crf_seg_kernel<128, 16><<<dim3(B, 16), 64, 0, stream>>>(logits, trans, lens, Qout, sig);
        crf_comb_kernel<128, 16><<<B, 64, 0, stream>>>(logits, trans, targets, lens, Qout, sig, out);
    } else {
        crf_fwd_fallback<<<B, 64, 0, stream>>>(logits, trans, targets, lens, out);
    }
}